// Round 2
// baseline (2318.580 us; speedup 1.0000x reference)
//
#include <hip/hip_runtime.h>
#include <math.h>

#define DIN 128
#define HID 16
#define DOUT 12
#define NMID 11

// ---------------------------------------------------------------------------
// CSC build: counting sort by col, stable (per-node insertion sort by edge id)
// so per-node accumulation order == original edge order == np.add.at order.
// edge_index arrives as int32 (harness converts integer inputs to int).
// ---------------------------------------------------------------------------

__global__ void count_kernel(const int* __restrict__ col,
                             int* __restrict__ counts, int E, int N) {
    int e = blockIdx.x * blockDim.x + threadIdx.x;
    if (e < E) {
        int c = col[e];
        if ((unsigned)c < (unsigned)N) atomicAdd(&counts[c], 1);
    }
}

// Single-block exclusive scan over n counts -> start[0..n], start[n] = total.
__global__ __launch_bounds__(1024)
void scan_kernel(const int* __restrict__ counts, int* __restrict__ start, int n) {
    __shared__ int wtot[16];
    __shared__ int s_carry;
    __shared__ int s_blocktotal;
    int tid = threadIdx.x;
    int lane = tid & 63;
    int wid = tid >> 6;
    if (tid == 0) s_carry = 0;
    __syncthreads();
    for (int base = 0; base < n; base += 1024) {
        int i = base + tid;
        int v = (i < n) ? counts[i] : 0;
        int x = v;
        for (int off = 1; off < 64; off <<= 1) {
            int y = __shfl_up(x, off, 64);
            if (lane >= off) x += y;
        }
        if (lane == 63) wtot[wid] = x;
        __syncthreads();
        if (wid == 0) {
            int t = (lane < 16) ? wtot[lane] : 0;
            for (int off = 1; off < 16; off <<= 1) {
                int y = __shfl_up(t, off, 64);
                if (lane >= off) t += y;
            }
            if (lane < 16) wtot[lane] = t;      // inclusive over waves
            if (lane == 15) s_blocktotal = t;
        }
        __syncthreads();
        int waveoff = (wid == 0) ? 0 : wtot[wid - 1];
        int excl = s_carry + waveoff + x - v;
        if (i < n) start[i] = excl;
        __syncthreads();
        if (tid == 0) s_carry += s_blocktotal;
        __syncthreads();
    }
    if (tid == 0) start[n] = s_carry;
}

__global__ void bucket_fill(const int* __restrict__ col,
                            const int* __restrict__ start,
                            int* __restrict__ cursor,
                            int* __restrict__ bucket, int E, int N) {
    int e = blockIdx.x * blockDim.x + threadIdx.x;
    if (e < E) {
        int c = col[e];
        if ((unsigned)c < (unsigned)N) {
            int p = start[c] + atomicAdd(&cursor[c], 1);
            bucket[p] = e;
        }
    }
}

// Sort each node's bucket slice ascending by edge id (stable order),
// then deg = (sum of w in edge order) + 1.0; dis = 1/sqrt(deg); selfw = 1/deg.
__global__ void node_sort_deg(int* __restrict__ bucket,
                              const int* __restrict__ start,
                              const float* __restrict__ w,
                              float* __restrict__ dis,
                              float* __restrict__ selfw, int N) {
    int i = blockIdx.x * blockDim.x + threadIdx.x;
    if (i >= N) return;
    int s = start[i], e = start[i + 1];
    for (int p = s + 1; p < e; p++) {
        int key = bucket[p];
        int q = p - 1;
        while (q >= s && bucket[q] > key) {
            bucket[q + 1] = bucket[q];
            q--;
        }
        bucket[q + 1] = key;
    }
    float d = 0.0f;
    for (int p = s; p < e; p++) d = __fadd_rn(d, w[bucket[p]]);
    d = __fadd_rn(d, 1.0f);
    dis[i] = 1.0f / __fsqrt_rn(d);   // two correct roundings == 1/np.sqrt
    selfw[i] = 1.0f / d;
}

// rowidx[p], norm[p] in CSC order: norm = (dis[row]*w)*dis[col], left-assoc.
// NOTE: rowidx may alias bucket (thread p reads bucket[p] then writes slot p).
__global__ void edge_prep(int* __restrict__ bucket_rowidx,
                          const int* __restrict__ row32,
                          const int* __restrict__ col32,
                          const float* __restrict__ w,
                          const float* __restrict__ dis,
                          float* __restrict__ normv, int E, int N) {
    int p = blockIdx.x * blockDim.x + threadIdx.x;
    if (p < E) {
        int e = bucket_rowidx[p];
        float nm = 0.0f;
        int r = 0;
        if ((unsigned)e < (unsigned)E) {
            r = row32[e];
            int c = col32[e];
            if ((unsigned)r < (unsigned)N && (unsigned)c < (unsigned)N) {
                nm = __fmul_rn(__fmul_rn(dis[r], w[e]), dis[c]);
            } else {
                r = 0;
            }
        }
        bucket_rowidx[p] = r;
        normv[p] = nm;
    }
}

// ---------------------------------------------------------------------------
// Layers
// ---------------------------------------------------------------------------

// hw[i][j] = sum_k h[i][k]*W[k][j], sequential in-order-k FMA (BLAS-like).
template <int F>
__global__ void gemm_k(const float* __restrict__ h, const float* __restrict__ W,
                       float* __restrict__ hw, int N, int K) {
    long g = (long)blockIdx.x * blockDim.x + threadIdx.x;
    int i = (int)(g / F);
    int j = (int)(g % F);
    if (i >= N) return;
    const float* hr = h + (long)i * K;
    float acc = 0.0f;
    for (int k = 0; k < K; k++) acc = fmaf(hr[k], W[k * F + j], acc);
    hw[(long)i * F + j] = acc;
}

// agg[i][f] = sum_{p in csc(i)} fadd(fmul(norm[p], hw[row[p]][f]))  (in order)
//           + fmul(selfw[i], hw[i][f]);  relu(agg + b[f]).
// 16 lanes per node (lanes >= F idle for F=12).
template <int F>
__global__ __launch_bounds__(256)
void agg_k(const float* __restrict__ hw, const int* __restrict__ rowidx,
           const float* __restrict__ normv, const int* __restrict__ start,
           const float* __restrict__ selfw, const float* __restrict__ bias,
           float* __restrict__ out, int N) {
    int g = blockIdx.x * blockDim.x + threadIdx.x;
    int node = g >> 4;
    int f = g & 15;
    if (node >= N || f >= F) return;
    int s = start[node], e = start[node + 1];
    float acc = 0.0f;
    for (int p = s; p < e; p++) {
        int r = rowidx[p];
        float nm = normv[p];
        acc = __fadd_rn(acc, __fmul_rn(nm, hw[(long)r * F + f]));
    }
    acc = __fadd_rn(acc, __fmul_rn(selfw[node], hw[(long)node * F + f]));
    acc = __fadd_rn(acc, bias[f]);
    out[(long)node * F + f] = fmaxf(acc, 0.0f);
}

// ---------------------------------------------------------------------------

extern "C" void kernel_launch(void* const* d_in, const int* in_sizes, int n_in,
                              void* d_out, int out_size, void* d_ws, size_t ws_size,
                              hipStream_t stream) {
    const float* x      = (const float*)d_in[0];
    const int*   ei     = (const int*)d_in[1];     // int64 in jax -> int32 here
    const float* ew     = (const float*)d_in[2];
    const float* W0     = (const float*)d_in[3];
    const float* b0     = (const float*)d_in[4];
    const float* Wmid   = (const float*)d_in[5];
    const float* bmid   = (const float*)d_in[6];
    const float* Wlast  = (const float*)d_in[7];
    const float* blast  = (const float*)d_in[8];

    const int N = in_sizes[0] / DIN;      // 100000
    const int E = in_sizes[2];            // 3200000
    const int* row32 = ei;                // edge_index[0]
    const int* col32 = ei + E;            // edge_index[1]

    // Workspace carve-up (256B aligned slabs). Total ~40.4 MB.
    char* w = (char*)d_ws;
    size_t off = 0;
    auto alloc = [&](size_t bytes) -> void* {
        void* p = w + off;
        off = (off + bytes + 255) & ~(size_t)255;
        return p;
    };
    int*   counts = (int*)alloc((size_t)N * 4);
    int*   cursor = (int*)alloc((size_t)N * 4);
    int*   start  = (int*)alloc((size_t)(N + 1) * 4);
    int*   bucket = (int*)alloc((size_t)E * 4);   // becomes rowidx after edge_prep
    float* normv  = (float*)alloc((size_t)E * 4);
    float* dis    = (float*)alloc((size_t)N * 4);
    float* selfw  = (float*)alloc((size_t)N * 4);
    float* hbuf   = (float*)alloc((size_t)N * HID * 4);
    float* hwbuf  = (float*)alloc((size_t)N * HID * 4);
    (void)ws_size;

    hipMemsetAsync(counts, 0, (size_t)N * 4, stream);
    hipMemsetAsync(cursor, 0, (size_t)N * 4, stream);

    const int B = 256;
    int gridE = (E + B - 1) / B;

    count_kernel<<<gridE, B, 0, stream>>>(col32, counts, E, N);
    scan_kernel<<<1, 1024, 0, stream>>>(counts, start, N);
    bucket_fill<<<gridE, B, 0, stream>>>(col32, start, cursor, bucket, E, N);
    node_sort_deg<<<(N + B - 1) / B, B, 0, stream>>>(bucket, start, ew, dis, selfw, N);
    edge_prep<<<gridE, B, 0, stream>>>(bucket, row32, col32, ew, dis, normv, E, N);
    int* rowidx = bucket;  // aliased, now holds row indices in CSC order

    int gridN16 = (N * 16 + B - 1) / B;
    int gridG16 = (N * 16 + B - 1) / B;
    int gridG12 = (N * 12 + B - 1) / B;

    // Layer 0: 128 -> 16
    gemm_k<HID><<<gridG16, B, 0, stream>>>(x, W0, hwbuf, N, DIN);
    agg_k<HID><<<gridN16, B, 0, stream>>>(hwbuf, rowidx, normv, start, selfw, b0, hbuf, N);

    // Middle layers: 16 -> 16
    for (int l = 0; l < NMID; l++) {
        gemm_k<HID><<<gridG16, B, 0, stream>>>(hbuf, Wmid + (size_t)l * HID * HID, hwbuf, N, HID);
        agg_k<HID><<<gridN16, B, 0, stream>>>(hwbuf, rowidx, normv, start, selfw,
                                              bmid + (size_t)l * HID, hbuf, N);
    }

    // Last layer: 16 -> 12
    gemm_k<DOUT><<<gridG12, B, 0, stream>>>(hbuf, Wlast, hwbuf, N, HID);
    agg_k<DOUT><<<gridN16, B, 0, stream>>>(hwbuf, rowidx, normv, start, selfw, blast,
                                           (float*)d_out, N);
}

// Round 3
// 2014.860 us; speedup vs baseline: 1.1507x; 1.1507x over previous
//
#include <hip/hip_runtime.h>
#include <math.h>

#define DIN 128
#define HID 16
#define DOUT 12
#define NMID 11

#define NB 196          // coarse buckets = ceil(100000/512)
#define CPB 512         // cols per bucket (col >> 9)
#define EPB 8192        // edges per binning block
#define TB 256          // threads per binning block

typedef unsigned long long ull;

// ---------------------------------------------------------------------------
// Deterministic stable CSC build (two-level binning, no sorts, no cross-block
// atomics). Global order within every node's edge list == original edge-id
// order == np.add.at accumulation order (sub-ulp absmax threshold requires it).
// ---------------------------------------------------------------------------

// S1: per-block histogram over coarse buckets.
__global__ __launch_bounds__(TB)
void s1_hist(const int* __restrict__ col, int* __restrict__ H,
             int E, int N) {
    __shared__ int hist[NB];
    int tid = threadIdx.x;
    for (int i = tid; i < NB; i += TB) hist[i] = 0;
    __syncthreads();
    long base = (long)blockIdx.x * EPB;
    for (int r = 0; r < EPB / TB; ++r) {
        long e = base + (long)r * TB + tid;
        if (e < E) {
            int c = col[e];
            if ((unsigned)c < (unsigned)N) atomicAdd(&hist[c >> 9], 1);
        }
    }
    __syncthreads();
    for (int i = tid; i < NB; i += TB) H[(long)blockIdx.x * NB + i] = hist[i];
}

// S2: bucket totals -> bucketStart (exclusive scan), and per-(block,bucket)
// deterministic reservation offsets O[k][b] (block-major order within bucket).
__global__ __launch_bounds__(256)
void s2_scan(const int* __restrict__ H, int* __restrict__ O,
             int* __restrict__ bucketStart, int nblk) {
    __shared__ int wtot[4];
    int tid = threadIdx.x;
    int lane = tid & 63, wid = tid >> 6;
    int total = 0;
    if (tid < NB)
        for (int k = 0; k < nblk; ++k) total += H[(long)k * NB + tid];
    int x = total;
    for (int off = 1; off < 64; off <<= 1) {
        int y = __shfl_up(x, off, 64);
        if (lane >= off) x += y;
    }
    if (lane == 63) wtot[wid] = x;
    __syncthreads();
    if (tid == 0) { int c = 0; for (int i = 0; i < 4; ++i) { int v = wtot[i]; wtot[i] = c; c += v; } }
    __syncthreads();
    int excl = wtot[wid] + x - total;
    if (tid < NB) {
        bucketStart[tid] = excl;
        if (tid == NB - 1) bucketStart[NB] = excl + total;
        int run = excl;
        for (int k = 0; k < nblk; ++k) {
            int h = H[(long)k * NB + tid];
            O[(long)k * NB + tid] = run;
            run += h;
        }
    }
}

// S3: stable scatter of (row, w, localCol) into reserved bucket runs.
// Within block: rounds ascend (edge-id major), waves serialized, within-wave
// rank via bit-ballot peer matching -> placement order == edge-id order.
__global__ __launch_bounds__(TB)
void s3_scatter(const int* __restrict__ row, const int* __restrict__ col,
                const float* __restrict__ ew, const int* __restrict__ O,
                int* __restrict__ binRow, float* __restrict__ binW,
                unsigned short* __restrict__ binColL,
                int E, int N) {
    __shared__ int cursor[NB];
    int tid = threadIdx.x;
    int lane = tid & 63, wid = tid >> 6;
    for (int i = tid; i < NB; i += TB) cursor[i] = O[(long)blockIdx.x * NB + i];
    __syncthreads();
    long base = (long)blockIdx.x * EPB;
    ull ltm = (lane == 0) ? 0ULL : ((~0ULL) >> (64 - lane));
    for (int r = 0; r < EPB / TB; ++r) {
        long e = base + (long)r * TB + tid;
        bool valid = (e < E);
        int c = 0, rw = 0; float wv = 0.f;
        if (valid) { c = col[e]; valid = ((unsigned)c < (unsigned)N); }
        if (valid) { rw = row[e]; wv = ew[e]; }
        int b = valid ? (c >> 9) : 0;
        ull vm = __ballot(valid);
        ull peers = vm;
        for (int bit = 0; bit < 8; ++bit) {
            ull s = __ballot(valid && ((b >> bit) & 1));
            peers &= ((b >> bit) & 1) ? s : ~s;
        }
        int rank = __popcll(peers & ltm);
        int cnt  = __popcll(peers);
        int ldr  = __ffsll((ull)peers) - 1;   // -1 only when peers==0 (invalid lane)
        if (ldr < 0) ldr = 0;
        int myoff = 0;
        for (int w = 0; w < TB / 64; ++w) {
            if (wid == w && valid && rank == 0) myoff = atomicAdd(&cursor[b], cnt);
            __syncthreads();
        }
        int off = __shfl(myoff, ldr, 64);
        if (valid) {
            int pos = off + rank;
            if ((unsigned)pos < (unsigned)E) {
                binRow[pos] = rw;
                binW[pos] = wv;
                binColL[pos] = (unsigned short)(c & (CPB - 1));
            }
        }
    }
}

// S4: per bucket: counting-scan by local col, stable placement to final CSC,
// write start[], then per-col in-edge-order deg sum -> dis, selfw.
__global__ __launch_bounds__(256)
void s4_bucket(const int* __restrict__ bucketStart,
               const int* __restrict__ binRow, const float* __restrict__ binW,
               const unsigned short* __restrict__ binColL,
               int* __restrict__ rowS, float* __restrict__ wS,
               int* __restrict__ start, float* __restrict__ dis,
               float* __restrict__ selfw, int E, int N) {
    __shared__ int hist[CPB];
    __shared__ int colStart[CPB + 1];
    __shared__ int cursor[CPB];
    __shared__ int wtot[4];
    int b = blockIdx.x;
    int tid = threadIdx.x;
    int lane = tid & 63, wid = tid >> 6;
    int segs = bucketStart[b], sege = bucketStart[b + 1];
    int len = sege - segs;
    for (int i = tid; i < CPB; i += 256) hist[i] = 0;
    __syncthreads();
    for (int p = segs + tid; p < sege; p += 256)
        atomicAdd(&hist[binColL[p] & (CPB - 1)], 1);
    __syncthreads();
    // exclusive scan of 512 histogram entries (2 per thread)
    int a0 = hist[2 * tid], a1 = hist[2 * tid + 1];
    int ps = a0 + a1;
    int x = ps;
    for (int off = 1; off < 64; off <<= 1) {
        int y = __shfl_up(x, off, 64);
        if (lane >= off) x += y;
    }
    if (lane == 63) wtot[wid] = x;
    __syncthreads();
    if (tid == 0) { int cc = 0; for (int i = 0; i < 4; ++i) { int v = wtot[i]; wtot[i] = cc; cc += v; } }
    __syncthreads();
    int exclp = wtot[wid] + x - ps;
    colStart[2 * tid] = exclp;
    colStart[2 * tid + 1] = exclp + a0;
    if (tid == 255) colStart[CPB] = exclp + ps;
    __syncthreads();
    for (int c = tid; c < CPB; c += 256) {
        int cg = b * CPB + c;
        if (cg < N) start[cg] = segs + colStart[c];
        cursor[c] = segs + colStart[c];
    }
    if (b == NB - 1 && tid == 0) start[N] = E;
    __syncthreads();
    // stable placement (rounds ascend edge-id, waves serialized, ballot rank)
    int rounds = (len + 255) / 256;
    ull ltm = (lane == 0) ? 0ULL : ((~0ULL) >> (64 - lane));
    for (int r = 0; r < rounds; ++r) {
        int p = segs + r * 256 + tid;
        bool valid = (p < sege);
        int c = valid ? ((int)binColL[p] & (CPB - 1)) : 0;
        int rw = 0; float wv = 0.f;
        if (valid) { rw = binRow[p]; wv = binW[p]; }
        ull vm = __ballot(valid);
        ull peers = vm;
        for (int bit = 0; bit < 9; ++bit) {
            ull s = __ballot(valid && ((c >> bit) & 1));
            peers &= ((c >> bit) & 1) ? s : ~s;
        }
        int rank = __popcll(peers & ltm);
        int cnt  = __popcll(peers);
        int ldr  = __ffsll((ull)peers) - 1;
        if (ldr < 0) ldr = 0;
        int myoff = 0;
        for (int w = 0; w < 4; ++w) {
            if (wid == w && valid && rank == 0) myoff = atomicAdd(&cursor[c], cnt);
            __syncthreads();
        }
        int off = __shfl(myoff, ldr, 64);
        if (valid) {
            int pos = off + rank;
            if ((unsigned)pos < (unsigned)E) { rowS[pos] = rw; wS[pos] = wv; }
        }
    }
    __threadfence_block();
    __syncthreads();
    // deg: strict in-edge-order left-assoc sum, then +1.0 (matches reference)
    for (int c = tid; c < CPB; c += 256) {
        int cg = b * CPB + c;
        if (cg >= N) continue;
        int s0 = segs + colStart[c], e0 = segs + colStart[c + 1];
        float d = 0.f;
        for (int p = s0; p < e0; ++p) d = __fadd_rn(d, wS[p]);
        d = __fadd_rn(d, 1.0f);
        dis[cg] = 1.0f / __fsqrt_rn(d);   // two correct roundings == 1/np.sqrt
        selfw[cg] = 1.0f / d;
    }
}

// S7: normv[p] = (dis[row]*w)*dis[col], left-assoc; iterate per col run.
__global__ __launch_bounds__(256)
void s7_norm(const int* __restrict__ start, const int* __restrict__ rowS,
             const float* __restrict__ wS, const float* __restrict__ dis,
             float* __restrict__ normv, int N) {
    int b = blockIdx.x;
    int tid = threadIdx.x;
    for (int c = tid; c < CPB; c += 256) {
        int cg = b * CPB + c;
        if (cg >= N) continue;
        int s0 = start[cg], e0 = start[cg + 1];
        float dc = dis[cg];
        for (int p = s0; p < e0; ++p)
            normv[p] = __fmul_rn(__fmul_rn(dis[rowS[p]], wS[p]), dc);
    }
}

// ---------------------------------------------------------------------------
// Layers (unchanged from passing version — bit-identical math)
// ---------------------------------------------------------------------------

template <int F>
__global__ void gemm_k(const float* __restrict__ h, const float* __restrict__ W,
                       float* __restrict__ hw, int N, int K) {
    long g = (long)blockIdx.x * blockDim.x + threadIdx.x;
    int i = (int)(g / F);
    int j = (int)(g % F);
    if (i >= N) return;
    const float* hr = h + (long)i * K;
    float acc = 0.0f;
    for (int k = 0; k < K; k++) acc = fmaf(hr[k], W[k * F + j], acc);
    hw[(long)i * F + j] = acc;
}

template <int F>
__global__ __launch_bounds__(256)
void agg_k(const float* __restrict__ hw, const int* __restrict__ rowidx,
           const float* __restrict__ normv, const int* __restrict__ start,
           const float* __restrict__ selfw, const float* __restrict__ bias,
           float* __restrict__ out, int N) {
    int g = blockIdx.x * blockDim.x + threadIdx.x;
    int node = g >> 4;
    int f = g & 15;
    if (node >= N || f >= F) return;
    int s = start[node], e = start[node + 1];
    float acc = 0.0f;
    for (int p = s; p < e; p++) {
        int r = rowidx[p];
        float nm = normv[p];
        acc = __fadd_rn(acc, __fmul_rn(nm, hw[(long)r * F + f]));
    }
    acc = __fadd_rn(acc, __fmul_rn(selfw[node], hw[(long)node * F + f]));
    acc = __fadd_rn(acc, bias[f]);
    out[(long)node * F + f] = fmaxf(acc, 0.0f);
}

// ---------------------------------------------------------------------------

extern "C" void kernel_launch(void* const* d_in, const int* in_sizes, int n_in,
                              void* d_out, int out_size, void* d_ws, size_t ws_size,
                              hipStream_t stream) {
    const float* x      = (const float*)d_in[0];
    const int*   ei     = (const int*)d_in[1];
    const float* ew     = (const float*)d_in[2];
    const float* W0     = (const float*)d_in[3];
    const float* b0     = (const float*)d_in[4];
    const float* Wmid   = (const float*)d_in[5];
    const float* bmid   = (const float*)d_in[6];
    const float* Wlast  = (const float*)d_in[7];
    const float* blast  = (const float*)d_in[8];

    const int N = in_sizes[0] / DIN;      // 100000
    const int E = in_sizes[2];            // 3200000
    const int* row32 = ei;
    const int* col32 = ei + E;
    const int nblk = (E + EPB - 1) / EPB; // 391

    // Workspace carve-up (256B aligned). Total ~60 MB.
    char* w = (char*)d_ws;
    size_t off = 0;
    auto alloc = [&](size_t bytes) -> void* {
        void* p = w + off;
        off = (off + bytes + 255) & ~(size_t)255;
        return p;
    };
    int*   H        = (int*)alloc((size_t)nblk * NB * 4);
    int*   O        = (int*)alloc((size_t)nblk * NB * 4);
    int*   bStart   = (int*)alloc((size_t)(NB + 1) * 4);
    int*   start    = (int*)alloc((size_t)(N + 1) * 4);
    float* dis      = (float*)alloc((size_t)N * 4);
    float* selfw    = (float*)alloc((size_t)N * 4);
    int*   rowS     = (int*)alloc((size_t)E * 4);
    float* wS       = (float*)alloc((size_t)E * 4);
    // region A: bin arrays, dead after s4 -> reused for normv/hbuf/hwbuf
    char*  regionA  = (char*)alloc((size_t)E * 4 + (size_t)E * 4 + (size_t)E * 2 + 1024);
    int*            binRow  = (int*)regionA;
    float*          binW    = (float*)(regionA + (size_t)E * 4);
    unsigned short* binColL = (unsigned short*)(regionA + (size_t)E * 8);
    // aliases (used only after s4 completes; normv over binRow, bufs over binW+)
    float* normv = (float*)regionA;
    float* hbuf  = (float*)(regionA + (size_t)E * 4);
    float* hwbuf = (float*)(regionA + (size_t)E * 4 + (size_t)N * HID * 4);
    (void)ws_size;

    // ---- setup: deterministic stable CSC ----
    s1_hist<<<nblk, TB, 0, stream>>>(col32, H, E, N);
    s2_scan<<<1, 256, 0, stream>>>(H, O, bStart, nblk);
    s3_scatter<<<nblk, TB, 0, stream>>>(row32, col32, ew, O, binRow, binW, binColL, E, N);
    s4_bucket<<<NB, 256, 0, stream>>>(bStart, binRow, binW, binColL,
                                      rowS, wS, start, dis, selfw, E, N);
    s7_norm<<<NB, 256, 0, stream>>>(start, rowS, wS, dis, normv, N);

    // ---- layers ----
    const int B = 256;
    int gridN16 = (N * 16 + B - 1) / B;
    int gridG12 = (N * 12 + B - 1) / B;

    gemm_k<HID><<<gridN16, B, 0, stream>>>(x, W0, hwbuf, N, DIN);
    agg_k<HID><<<gridN16, B, 0, stream>>>(hwbuf, rowS, normv, start, selfw, b0, hbuf, N);

    for (int l = 0; l < NMID; l++) {
        gemm_k<HID><<<gridN16, B, 0, stream>>>(hbuf, Wmid + (size_t)l * HID * HID, hwbuf, N, HID);
        agg_k<HID><<<gridN16, B, 0, stream>>>(hwbuf, rowS, normv, start, selfw,
                                              bmid + (size_t)l * HID, hbuf, N);
    }

    gemm_k<DOUT><<<gridG12, B, 0, stream>>>(hbuf, Wlast, hwbuf, N, HID);
    agg_k<DOUT><<<gridN16, B, 0, stream>>>(hwbuf, rowS, normv, start, selfw, blast,
                                           (float*)d_out, N);
}

// Round 4
// 1347.907 us; speedup vs baseline: 1.7201x; 1.4948x over previous
//
#include <hip/hip_runtime.h>
#include <math.h>

#define DIN 128
#define HID 16
#define DOUT 12
#define NMID 11

#define CPB 128        // cols per bucket (col >> 7)
#define NBMAX 800      // max coarse buckets (runtime 782)
#define EPB 4096       // edges per binning block
#define CAP 5120       // max edges per bucket in s4 LDS (mean 4092, sigma ~64)

typedef unsigned long long ull;

// exclusive scan in place over arr[0..L), 256 threads, L <= 1024
__device__ __forceinline__ void scan4(int* arr, int L, int tid, int* wtot) {
    int lane = tid & 63, wid = tid >> 6;
    int v[4]; int s = 0;
#pragma unroll
    for (int j = 0; j < 4; ++j) {
        int idx = tid * 4 + j;
        int t = (idx < L) ? arr[idx] : 0;
        v[j] = s; s += t;
    }
    int x = s;
    for (int off = 1; off < 64; off <<= 1) {
        int y = __shfl_up(x, off, 64);
        if (lane >= off) x += y;
    }
    if (lane == 63) wtot[wid] = x;
    __syncthreads();
    if (tid == 0) { int c = 0; for (int i = 0; i < 4; ++i) { int t = wtot[i]; wtot[i] = c; c += t; } }
    __syncthreads();
    int b0 = wtot[wid] + (x - s);
#pragma unroll
    for (int j = 0; j < 4; ++j) {
        int idx = tid * 4 + j;
        if (idx < L) arr[idx] = b0 + v[j];
    }
    __syncthreads();
}

// S1: per-block coarse histogram + global bucket totals (int atomics, exact).
__global__ __launch_bounds__(256)
void s1_hist(const int* __restrict__ col, int* __restrict__ H, int* __restrict__ T,
             int E, int N, int NB) {
    __shared__ int hist[NBMAX];
    int tid = threadIdx.x;
    for (int i = tid; i < NB; i += 256) hist[i] = 0;
    __syncthreads();
    long base = (long)blockIdx.x * EPB;
    for (int r = 0; r < EPB / 256; ++r) {
        long e = base + r * 256 + tid;
        if (e < E) {
            int c = col[e];
            if ((unsigned)c < (unsigned)N) atomicAdd(&hist[c >> 7], 1);
        }
    }
    __syncthreads();
    for (int i = tid; i < NB; i += 256) {
        int h = hist[i];
        H[(long)blockIdx.x * NB + i] = h;
        if (h) atomicAdd(&T[i], h);
    }
}

// S2b: exclusive scan of bucket totals -> bStart[0..NB], single block.
__global__ __launch_bounds__(1024)
void s2b_scan(const int* __restrict__ T, int* __restrict__ bStart, int NB) {
    __shared__ int wtot[16];
    int tid = threadIdx.x, lane = tid & 63, wid = tid >> 6;
    int v = (tid < NB) ? T[tid] : 0;
    int x = v;
    for (int off = 1; off < 64; off <<= 1) {
        int y = __shfl_up(x, off, 64);
        if (lane >= off) x += y;
    }
    if (lane == 63) wtot[wid] = x;
    __syncthreads();
    if (tid == 0) { int c = 0; for (int i = 0; i < 16; ++i) { int t = wtot[i]; wtot[i] = c; c += t; } }
    __syncthreads();
    int excl = wtot[wid] + x - v;
    if (tid < NB) {
        bStart[tid] = excl;
        if (tid == NB - 1) bStart[NB] = excl + v;
    }
}

// S2c: per-(block,bucket) reservation offsets, block-major within bucket.
// Lockstep threads -> coalesced column walks of H/O.
__global__ __launch_bounds__(256)
void s2c_off(const int* __restrict__ H, const int* __restrict__ bStart,
             int* __restrict__ O, int NB, int nblk) {
    int b = blockIdx.x * 256 + threadIdx.x;
    if (b >= NB) return;
    int run = bStart[b];
    for (int k = 0; k < nblk; ++k) {
        O[(long)k * NB + b] = run;
        run += H[(long)k * NB + b];
    }
}

// S3: stable bin by coarse bucket. Place into LDS (bucket-contiguous, stable
// edge-id order), then flush packed int2(row|colL<<17, w) with coalesced,
// near-full-line global writes. No 4B scatters to HBM.
__global__ __launch_bounds__(256)
void s3_bin(const int* __restrict__ row, const int* __restrict__ col,
            const float* __restrict__ ew, const int* __restrict__ O,
            int2* __restrict__ bins, int E, int N, int NB) {
    __shared__ int cnt[NBMAX];
    __shared__ int dlt[NBMAX];
    __shared__ int2 ldata[EPB];
    __shared__ int gdst[EPB];
    __shared__ int wtot[4];
    int tid = threadIdx.x;
    int lane = tid & 63, wid = tid >> 6;
    long base = (long)blockIdx.x * EPB;
    for (int i = tid; i < NB; i += 256) cnt[i] = 0;
    __syncthreads();
    // pass A: local histogram (order-free)
    for (int r = 0; r < EPB / 256; ++r) {
        long e = base + r * 256 + tid;
        if (e < E) {
            int c = col[e];
            if ((unsigned)c < (unsigned)N) atomicAdd(&cnt[c >> 7], 1);
        }
    }
    __syncthreads();
    scan4(cnt, NB, tid, wtot);   // cnt = local exclusive offsets (then cursor)
    for (int i = tid; i < NB; i += 256)
        dlt[i] = O[(long)blockIdx.x * NB + i] - cnt[i];   // gpos = lpos + dlt[b]
    __syncthreads();
    // pass B: stable placement (rounds ascend edge id, waves serialized,
    // within-wave rank via ballot peer matching)
    ull ltm = (lane == 0) ? 0ULL : ((~0ULL) >> (64 - lane));
    for (int r = 0; r < EPB / 256; ++r) {
        long e = base + r * 256 + tid;
        bool valid = (e < E);
        int c = 0;
        if (valid) { c = col[e]; valid = ((unsigned)c < (unsigned)N); }
        int b = valid ? (c >> 7) : 0;
        int rw = 0; float wv = 0.f;
        if (valid) { rw = row[e]; wv = ew[e]; }
        ull vm = __ballot(valid);
        ull peers = vm;
        for (int bit = 0; bit < 10; ++bit) {
            ull s = __ballot(valid && ((b >> bit) & 1));
            peers &= ((b >> bit) & 1) ? s : ~s;
        }
        int rank = __popcll(peers & ltm);
        int cng  = __popcll(peers);
        int ldr  = __ffsll(peers) - 1;
        if (ldr < 0) ldr = 0;
        int lb = 0;
        for (int w = 0; w < 4; ++w) {
            if (wid == w && valid && rank == 0) lb = atomicAdd(&cnt[b], cng);
            __syncthreads();
        }
        int lbase = __shfl(lb, ldr, 64);
        if (valid) {
            int lpos = lbase + rank;
            if ((unsigned)lpos < (unsigned)EPB) {
                ldata[lpos] = make_int2(rw | ((c & (CPB - 1)) << 17), __float_as_int(wv));
                gdst[lpos]  = lpos + dlt[b];
            }
        }
    }
    __syncthreads();
    int lenBlock = (int)((E - base < (long)EPB) ? (E - base) : (long)EPB);
    for (int p = tid; p < lenBlock; p += 256) {
        int g = gdst[p];
        if ((unsigned)g < (unsigned)E) bins[g] = ldata[p];
    }
}

// S4: per bucket stable counting sort by local col into LDS, coalesced flush
// of final CSC epack(row, w), start[], then per-col in-edge-order deg sums.
// NOTE: bins is read fully before being overwritten (same pointer = epack).
__global__ __launch_bounds__(256)
void s4_sort(const int* __restrict__ bStart, int2* bins,
             int* __restrict__ start, float* __restrict__ dis,
             float* __restrict__ selfw, int E, int N) {
    __shared__ int2 ldata[CAP];
    __shared__ int hist[CPB];
    __shared__ int colStart[CPB + 1];
    __shared__ int cursor[CPB];
    __shared__ int wtot[4];
    int b = blockIdx.x;
    int tid = threadIdx.x;
    int lane = tid & 63, wid = tid >> 6;
    int segs = bStart[b], sege = bStart[b + 1];
    int len = sege - segs;
    if (len > CAP) len = CAP;          // impossible-case guard
    if (tid < CPB) hist[tid] = 0;
    __syncthreads();
    for (int p = tid; p < len; p += 256)
        atomicAdd(&hist[(bins[segs + p].x >> 17) & (CPB - 1)], 1);
    __syncthreads();
    if (tid < CPB) colStart[tid] = hist[tid];
    __syncthreads();
    scan4(colStart, CPB, tid, wtot);
    if (tid == 0) colStart[CPB] = len;
    if (tid < CPB) {
        int cg = b * CPB + tid;
        if (cg < N) start[cg] = segs + colStart[tid];
        cursor[tid] = colStart[tid];
    }
    if (b == (int)gridDim.x - 1 && tid == 0) start[N] = sege;
    __syncthreads();
    int rounds = (len + 255) / 256;
    ull ltm = (lane == 0) ? 0ULL : ((~0ULL) >> (64 - lane));
    for (int r = 0; r < rounds; ++r) {
        int p = r * 256 + tid;
        bool valid = (p < len);
        int2 d = valid ? bins[segs + p] : make_int2(0, 0);
        int c = valid ? ((d.x >> 17) & (CPB - 1)) : 0;
        ull vm = __ballot(valid);
        ull peers = vm;
        for (int bit = 0; bit < 7; ++bit) {
            ull s = __ballot(valid && ((c >> bit) & 1));
            peers &= ((c >> bit) & 1) ? s : ~s;
        }
        int rank = __popcll(peers & ltm);
        int cng  = __popcll(peers);
        int ldr  = __ffsll(peers) - 1;
        if (ldr < 0) ldr = 0;
        int lb = 0;
        for (int w = 0; w < 4; ++w) {
            if (wid == w && valid && rank == 0) lb = atomicAdd(&cursor[c], cng);
            __syncthreads();
        }
        int lbase = __shfl(lb, ldr, 64);
        if (valid) {
            int lpos = lbase + rank;
            if ((unsigned)lpos < (unsigned)CAP) ldata[lpos] = d;
        }
    }
    __syncthreads();
    // coalesced flush: epack = (row, w bits)
    for (int p = tid; p < len; p += 256) {
        int2 d = ldata[p];
        bins[segs + p] = make_int2(d.x & 0x1FFFF, d.y);
    }
    // deg: strict in-edge-order left-assoc sum over the col run (from LDS)
    if (tid < CPB) {
        int cg = b * CPB + tid;
        if (cg < N) {
            int s0 = colStart[tid], e0 = colStart[tid + 1];
            float dsum = 0.f;
            for (int q = s0; q < e0; ++q)
                dsum = __fadd_rn(dsum, __int_as_float(ldata[q].y));
            dsum = __fadd_rn(dsum, 1.0f);
            dis[cg] = 1.0f / __fsqrt_rn(dsum);   // == 1/np.sqrt
            selfw[cg] = 1.0f / dsum;
        }
    }
}

// S7: epack.y: w -> norm = (dis[row]*w)*dis[col], left-assoc. In-place int2.
__global__ __launch_bounds__(256)
void s7_norm(const int* __restrict__ start, int2* __restrict__ epack,
             const float* __restrict__ dis, int N) {
    int cg = blockIdx.x * 256 + threadIdx.x;
    if (cg >= N) return;
    int s0 = start[cg], e0 = start[cg + 1];
    float dc = dis[cg];
    for (int p = s0; p < e0; ++p) {
        int2 d = epack[p];
        float nm = __fmul_rn(__fmul_rn(dis[d.x], __int_as_float(d.y)), dc);
        epack[p] = make_int2(d.x, __float_as_int(nm));
    }
}

// ---------------------------------------------------------------------------
// Layers: 4 threads per node, float4 lanes. Per-scalar op order identical to
// the verified round-2 kernels (sequential-k fmaf; edge-order fadd/fmul).
// ---------------------------------------------------------------------------

template <int F>
__global__ __launch_bounds__(256)
void gemm4(const float* __restrict__ h, const float* __restrict__ W,
           float* __restrict__ hw, int N, int K) {
    int g = blockIdx.x * 256 + threadIdx.x;
    int i = g >> 2, jq = g & 3;
    if (i >= N) return;
    if (jq * 4 >= F) return;
    const float4* hv = (const float4*)(h + (long)i * K);
    const float4* Wv = (const float4*)W;
    float4 acc = make_float4(0.f, 0.f, 0.f, 0.f);
    for (int k4 = 0; k4 < K / 4; ++k4) {
        float4 h4 = hv[k4];
        float4 w0 = Wv[(4 * k4 + 0) * (F / 4) + jq];
        acc.x = fmaf(h4.x, w0.x, acc.x); acc.y = fmaf(h4.x, w0.y, acc.y);
        acc.z = fmaf(h4.x, w0.z, acc.z); acc.w = fmaf(h4.x, w0.w, acc.w);
        float4 w1 = Wv[(4 * k4 + 1) * (F / 4) + jq];
        acc.x = fmaf(h4.y, w1.x, acc.x); acc.y = fmaf(h4.y, w1.y, acc.y);
        acc.z = fmaf(h4.y, w1.z, acc.z); acc.w = fmaf(h4.y, w1.w, acc.w);
        float4 w2 = Wv[(4 * k4 + 2) * (F / 4) + jq];
        acc.x = fmaf(h4.z, w2.x, acc.x); acc.y = fmaf(h4.z, w2.y, acc.y);
        acc.z = fmaf(h4.z, w2.z, acc.z); acc.w = fmaf(h4.z, w2.w, acc.w);
        float4 w3 = Wv[(4 * k4 + 3) * (F / 4) + jq];
        acc.x = fmaf(h4.w, w3.x, acc.x); acc.y = fmaf(h4.w, w3.y, acc.y);
        acc.z = fmaf(h4.w, w3.z, acc.z); acc.w = fmaf(h4.w, w3.w, acc.w);
    }
    ((float4*)hw)[(long)i * (F / 4) + jq] = acc;
}

template <int F>
__global__ __launch_bounds__(256)
void agg4(const float* __restrict__ hw, const int2* __restrict__ epack,
          const int* __restrict__ start, const float* __restrict__ selfw,
          const float* __restrict__ bias, float* __restrict__ out, int N) {
    int g = blockIdx.x * 256 + threadIdx.x;
    int node = g >> 2, fq = g & 3;
    if (node >= N) return;
    if (fq * 4 >= F) return;
    const float4* hwv = (const float4*)hw;
    int s = start[node], e = start[node + 1];
    float4 acc = make_float4(0.f, 0.f, 0.f, 0.f);
    for (int p = s; p < e; ++p) {
        int2 d = epack[p];
        float nm = __int_as_float(d.y);
        float4 gv = hwv[(long)d.x * (F / 4) + fq];
        acc.x = __fadd_rn(acc.x, __fmul_rn(nm, gv.x));
        acc.y = __fadd_rn(acc.y, __fmul_rn(nm, gv.y));
        acc.z = __fadd_rn(acc.z, __fmul_rn(nm, gv.z));
        acc.w = __fadd_rn(acc.w, __fmul_rn(nm, gv.w));
    }
    float sw = selfw[node];
    float4 sv = hwv[(long)node * (F / 4) + fq];
    acc.x = __fadd_rn(acc.x, __fmul_rn(sw, sv.x));
    acc.y = __fadd_rn(acc.y, __fmul_rn(sw, sv.y));
    acc.z = __fadd_rn(acc.z, __fmul_rn(sw, sv.z));
    acc.w = __fadd_rn(acc.w, __fmul_rn(sw, sv.w));
    float4 bv = ((const float4*)bias)[fq];
    acc.x = fmaxf(__fadd_rn(acc.x, bv.x), 0.f);
    acc.y = fmaxf(__fadd_rn(acc.y, bv.y), 0.f);
    acc.z = fmaxf(__fadd_rn(acc.z, bv.z), 0.f);
    acc.w = fmaxf(__fadd_rn(acc.w, bv.w), 0.f);
    ((float4*)out)[(long)node * (F / 4) + fq] = acc;
}

// ---------------------------------------------------------------------------

extern "C" void kernel_launch(void* const* d_in, const int* in_sizes, int n_in,
                              void* d_out, int out_size, void* d_ws, size_t ws_size,
                              hipStream_t stream) {
    const float* x      = (const float*)d_in[0];
    const int*   ei     = (const int*)d_in[1];
    const float* ew     = (const float*)d_in[2];
    const float* W0     = (const float*)d_in[3];
    const float* b0     = (const float*)d_in[4];
    const float* Wmid   = (const float*)d_in[5];
    const float* bmid   = (const float*)d_in[6];
    const float* Wlast  = (const float*)d_in[7];
    const float* blast  = (const float*)d_in[8];

    const int N = in_sizes[0] / DIN;              // 100000
    const int E = in_sizes[2];                    // 3200000
    const int* row32 = ei;
    const int* col32 = ei + E;
    const int nblk = (E + EPB - 1) / EPB;         // 782
    const int NB   = (N + CPB - 1) / CPB;         // 782 (<= NBMAX)

    char* w = (char*)d_ws;
    size_t off = 0;
    auto alloc = [&](size_t bytes) -> void* {
        void* p = w + off;
        off = (off + bytes + 255) & ~(size_t)255;
        return p;
    };
    int*  T      = (int*)alloc((size_t)NB * 4);
    int*  bStart = (int*)alloc((size_t)(NB + 1) * 4);
    int*  H      = (int*)alloc((size_t)nblk * NB * 4);
    int*  O      = (int*)alloc((size_t)nblk * NB * 4);
    int*  start  = (int*)alloc((size_t)(N + 1) * 4);
    float* dis   = (float*)alloc((size_t)N * 4);
    float* selfw = (float*)alloc((size_t)N * 4);
    int2* bins   = (int2*)alloc((size_t)E * 8);   // s3 out; becomes epack in s4
    float* hbuf  = (float*)alloc((size_t)N * HID * 4);
    float* hwbuf = (float*)alloc((size_t)N * HID * 4);
    (void)ws_size;

    hipMemsetAsync(T, 0, (size_t)NB * 4, stream);

    s1_hist<<<nblk, 256, 0, stream>>>(col32, H, T, E, N, NB);
    s2b_scan<<<1, 1024, 0, stream>>>(T, bStart, NB);
    s2c_off<<<(NB + 255) / 256, 256, 0, stream>>>(H, bStart, O, NB, nblk);
    s3_bin<<<nblk, 256, 0, stream>>>(row32, col32, ew, O, bins, E, N, NB);
    s4_sort<<<NB, 256, 0, stream>>>(bStart, bins, start, dis, selfw, E, N);
    s7_norm<<<(N + 255) / 256, 256, 0, stream>>>(start, bins, dis, N);
    int2* epack = bins;

    int gridN4 = (N * 4 + 255) / 256;

    gemm4<HID><<<gridN4, 256, 0, stream>>>(x, W0, hwbuf, N, DIN);
    agg4<HID><<<gridN4, 256, 0, stream>>>(hwbuf, epack, start, selfw, b0, hbuf, N);

    for (int l = 0; l < NMID; l++) {
        gemm4<HID><<<gridN4, 256, 0, stream>>>(hbuf, Wmid + (size_t)l * HID * HID, hwbuf, N, HID);
        agg4<HID><<<gridN4, 256, 0, stream>>>(hwbuf, epack, start, selfw,
                                              bmid + (size_t)l * HID, hbuf, N);
    }

    gemm4<DOUT><<<gridN4, 256, 0, stream>>>(hbuf, Wlast, hwbuf, N, HID);
    agg4<DOUT><<<gridN4, 256, 0, stream>>>(hwbuf, epack, start, selfw, blast,
                                           (float*)d_out, N);
}

// Round 5
// 1169.751 us; speedup vs baseline: 1.9821x; 1.1523x over previous
//
#include <hip/hip_runtime.h>
#include <math.h>

#define DIN 128
#define HID 16
#define DOUT 12
#define NMID 11

#define CPB 128        // cols per bucket (col >> 7)
#define NBMAX 800      // max coarse buckets (runtime 782)
#define EPB 4096       // edges per binning block
#define CAP 5120       // max edges per bucket in s4 LDS (mean 4092, sigma ~64)

typedef unsigned long long ull;

// exclusive scan in place over arr[0..L), 256 threads, L <= 1024
__device__ __forceinline__ void scan4(int* arr, int L, int tid, int* wtot) {
    int lane = tid & 63, wid = tid >> 6;
    int v[4]; int s = 0;
#pragma unroll
    for (int j = 0; j < 4; ++j) {
        int idx = tid * 4 + j;
        int t = (idx < L) ? arr[idx] : 0;
        v[j] = s; s += t;
    }
    int x = s;
    for (int off = 1; off < 64; off <<= 1) {
        int y = __shfl_up(x, off, 64);
        if (lane >= off) x += y;
    }
    if (lane == 63) wtot[wid] = x;
    __syncthreads();
    if (tid == 0) { int c = 0; for (int i = 0; i < 4; ++i) { int t = wtot[i]; wtot[i] = c; c += t; } }
    __syncthreads();
    int b0 = wtot[wid] + (x - s);
#pragma unroll
    for (int j = 0; j < 4; ++j) {
        int idx = tid * 4 + j;
        if (idx < L) arr[idx] = b0 + v[j];
    }
    __syncthreads();
}

// S1: per-block coarse histogram + global bucket totals (int atomics, exact).
__global__ __launch_bounds__(256)
void s1_hist(const int* __restrict__ col, int* __restrict__ H, int* __restrict__ T,
             int E, int N, int NB) {
    __shared__ int hist[NBMAX];
    int tid = threadIdx.x;
    for (int i = tid; i < NB; i += 256) hist[i] = 0;
    __syncthreads();
    long base = (long)blockIdx.x * EPB;
    for (int r = 0; r < EPB / 256; ++r) {
        long e = base + r * 256 + tid;
        if (e < E) {
            int c = col[e];
            if ((unsigned)c < (unsigned)N) atomicAdd(&hist[c >> 7], 1);
        }
    }
    __syncthreads();
    for (int i = tid; i < NB; i += 256) {
        int h = hist[i];
        H[(long)blockIdx.x * NB + i] = h;
        if (h) atomicAdd(&T[i], h);
    }
}

// S2b: exclusive scan of bucket totals -> bStart[0..NB], single block.
__global__ __launch_bounds__(1024)
void s2b_scan(const int* __restrict__ T, int* __restrict__ bStart, int NB) {
    __shared__ int wtot[16];
    int tid = threadIdx.x, lane = tid & 63, wid = tid >> 6;
    int v = (tid < NB) ? T[tid] : 0;
    int x = v;
    for (int off = 1; off < 64; off <<= 1) {
        int y = __shfl_up(x, off, 64);
        if (lane >= off) x += y;
    }
    if (lane == 63) wtot[wid] = x;
    __syncthreads();
    if (tid == 0) { int c = 0; for (int i = 0; i < 16; ++i) { int t = wtot[i]; wtot[i] = c; c += t; } }
    __syncthreads();
    int excl = wtot[wid] + x - v;
    if (tid < NB) {
        bStart[tid] = excl;
        if (tid == NB - 1) bStart[NB] = excl + v;
    }
}

// S2c: per-(block,bucket) reservation offsets. One WAVE per bucket: segmented
// wave-64 scan over the block axis (13 chunks of 64). 782 waves spread over
// the whole GPU (replaces the 4-block serial column walk that ran at 0.15%
// occupancy / 196 us).
__global__ __launch_bounds__(256)
void s2c_scan(const int* __restrict__ H, const int* __restrict__ bStart,
              int* __restrict__ O, int NB, int nblk) {
    int wv = (blockIdx.x * 256 + threadIdx.x) >> 6;   // wave id == bucket
    int lane = threadIdx.x & 63;
    if (wv >= NB) return;
    int run = bStart[wv];
    for (int k0 = 0; k0 < nblk; k0 += 64) {
        int k = k0 + lane;
        int h = (k < nblk) ? H[(long)k * NB + wv] : 0;
        int x = h;
        for (int off = 1; off < 64; off <<= 1) {
            int y = __shfl_up(x, off, 64);
            if (lane >= off) x += y;
        }
        if (k < nblk) O[(long)k * NB + wv] = run + (x - h);
        run += __shfl(x, 63, 64);   // chunk total
    }
}

// S3: stable bin by coarse bucket. Place into LDS (bucket-contiguous, stable
// edge-id order), then flush packed int2(row|colL<<17, w) with coalesced,
// near-full-line global writes. No 4B scatters to HBM.
__global__ __launch_bounds__(256)
void s3_bin(const int* __restrict__ row, const int* __restrict__ col,
            const float* __restrict__ ew, const int* __restrict__ O,
            int2* __restrict__ bins, int E, int N, int NB) {
    __shared__ int cnt[NBMAX];
    __shared__ int dlt[NBMAX];
    __shared__ int2 ldata[EPB];
    __shared__ int gdst[EPB];
    __shared__ int wtot[4];
    int tid = threadIdx.x;
    int lane = tid & 63, wid = tid >> 6;
    long base = (long)blockIdx.x * EPB;
    for (int i = tid; i < NB; i += 256) cnt[i] = 0;
    __syncthreads();
    // pass A: local histogram (order-free)
    for (int r = 0; r < EPB / 256; ++r) {
        long e = base + r * 256 + tid;
        if (e < E) {
            int c = col[e];
            if ((unsigned)c < (unsigned)N) atomicAdd(&cnt[c >> 7], 1);
        }
    }
    __syncthreads();
    scan4(cnt, NB, tid, wtot);   // cnt = local exclusive offsets (then cursor)
    for (int i = tid; i < NB; i += 256)
        dlt[i] = O[(long)blockIdx.x * NB + i] - cnt[i];   // gpos = lpos + dlt[b]
    __syncthreads();
    // pass B: stable placement (rounds ascend edge id, waves serialized,
    // within-wave rank via ballot peer matching)
    ull ltm = (lane == 0) ? 0ULL : ((~0ULL) >> (64 - lane));
    for (int r = 0; r < EPB / 256; ++r) {
        long e = base + r * 256 + tid;
        bool valid = (e < E);
        int c = 0;
        if (valid) { c = col[e]; valid = ((unsigned)c < (unsigned)N); }
        int b = valid ? (c >> 7) : 0;
        int rw = 0; float wv = 0.f;
        if (valid) { rw = row[e]; wv = ew[e]; }
        ull vm = __ballot(valid);
        ull peers = vm;
        for (int bit = 0; bit < 10; ++bit) {
            ull s = __ballot(valid && ((b >> bit) & 1));
            peers &= ((b >> bit) & 1) ? s : ~s;
        }
        int rank = __popcll(peers & ltm);
        int cng  = __popcll(peers);
        int ldr  = __ffsll(peers) - 1;
        if (ldr < 0) ldr = 0;
        int lb = 0;
        for (int w = 0; w < 4; ++w) {
            if (wid == w && valid && rank == 0) lb = atomicAdd(&cnt[b], cng);
            __syncthreads();
        }
        int lbase = __shfl(lb, ldr, 64);
        if (valid) {
            int lpos = lbase + rank;
            if ((unsigned)lpos < (unsigned)EPB) {
                ldata[lpos] = make_int2(rw | ((c & (CPB - 1)) << 17), __float_as_int(wv));
                gdst[lpos]  = lpos + dlt[b];
            }
        }
    }
    __syncthreads();
    int lenBlock = (int)((E - base < (long)EPB) ? (E - base) : (long)EPB);
    for (int p = tid; p < lenBlock; p += 256) {
        int g = gdst[p];
        if ((unsigned)g < (unsigned)E) bins[g] = ldata[p];
    }
}

// S4: per bucket stable counting sort by local col into LDS, coalesced flush
// of final CSC epack(row, w), start[], then per-col in-edge-order deg sums.
// NOTE: bins is read fully before being overwritten (same pointer = epack).
__global__ __launch_bounds__(256)
void s4_sort(const int* __restrict__ bStart, int2* bins,
             int* __restrict__ start, float* __restrict__ dis,
             float* __restrict__ selfw, int E, int N) {
    __shared__ int2 ldata[CAP];
    __shared__ int hist[CPB];
    __shared__ int colStart[CPB + 1];
    __shared__ int cursor[CPB];
    __shared__ int wtot[4];
    int b = blockIdx.x;
    int tid = threadIdx.x;
    int lane = tid & 63, wid = tid >> 6;
    int segs = bStart[b], sege = bStart[b + 1];
    int len = sege - segs;
    if (len > CAP) len = CAP;          // impossible-case guard
    if (tid < CPB) hist[tid] = 0;
    __syncthreads();
    for (int p = tid; p < len; p += 256)
        atomicAdd(&hist[(bins[segs + p].x >> 17) & (CPB - 1)], 1);
    __syncthreads();
    if (tid < CPB) colStart[tid] = hist[tid];
    __syncthreads();
    scan4(colStart, CPB, tid, wtot);
    if (tid == 0) colStart[CPB] = len;
    if (tid < CPB) {
        int cg = b * CPB + tid;
        if (cg < N) start[cg] = segs + colStart[tid];
        cursor[tid] = colStart[tid];
    }
    if (b == (int)gridDim.x - 1 && tid == 0) start[N] = sege;
    __syncthreads();
    int rounds = (len + 255) / 256;
    ull ltm = (lane == 0) ? 0ULL : ((~0ULL) >> (64 - lane));
    for (int r = 0; r < rounds; ++r) {
        int p = r * 256 + tid;
        bool valid = (p < len);
        int2 d = valid ? bins[segs + p] : make_int2(0, 0);
        int c = valid ? ((d.x >> 17) & (CPB - 1)) : 0;
        ull vm = __ballot(valid);
        ull peers = vm;
        for (int bit = 0; bit < 7; ++bit) {
            ull s = __ballot(valid && ((c >> bit) & 1));
            peers &= ((c >> bit) & 1) ? s : ~s;
        }
        int rank = __popcll(peers & ltm);
        int cng  = __popcll(peers);
        int ldr  = __ffsll(peers) - 1;
        if (ldr < 0) ldr = 0;
        int lb = 0;
        for (int w = 0; w < 4; ++w) {
            if (wid == w && valid && rank == 0) lb = atomicAdd(&cursor[c], cng);
            __syncthreads();
        }
        int lbase = __shfl(lb, ldr, 64);
        if (valid) {
            int lpos = lbase + rank;
            if ((unsigned)lpos < (unsigned)CAP) ldata[lpos] = d;
        }
    }
    __syncthreads();
    // coalesced flush: epack = (row, w bits)
    for (int p = tid; p < len; p += 256) {
        int2 d = ldata[p];
        bins[segs + p] = make_int2(d.x & 0x1FFFF, d.y);
    }
    // deg: strict in-edge-order left-assoc sum over the col run (from LDS)
    if (tid < CPB) {
        int cg = b * CPB + tid;
        if (cg < N) {
            int s0 = colStart[tid], e0 = colStart[tid + 1];
            float dsum = 0.f;
            for (int q = s0; q < e0; ++q)
                dsum = __fadd_rn(dsum, __int_as_float(ldata[q].y));
            dsum = __fadd_rn(dsum, 1.0f);
            dis[cg] = 1.0f / __fsqrt_rn(dsum);   // == 1/np.sqrt
            selfw[cg] = 1.0f / dsum;
        }
    }
}

// S7: epack.y: w -> norm = (dis[row]*w)*dis[col], left-assoc. In-place int2.
__global__ __launch_bounds__(256)
void s7_norm(const int* __restrict__ start, int2* __restrict__ epack,
             const float* __restrict__ dis, int N) {
    int cg = blockIdx.x * 256 + threadIdx.x;
    if (cg >= N) return;
    int s0 = start[cg], e0 = start[cg + 1];
    float dc = dis[cg];
    for (int p = s0; p < e0; ++p) {
        int2 d = epack[p];
        float nm = __fmul_rn(__fmul_rn(dis[d.x], __int_as_float(d.y)), dc);
        epack[p] = make_int2(d.x, __float_as_int(nm));
    }
}

// ---------------------------------------------------------------------------
// Layers: 4 threads per node, float4 lanes. Per-scalar op order identical to
// the verified round-2 kernels (sequential-k fmaf; edge-order fadd/fmul).
// ---------------------------------------------------------------------------

template <int F>
__global__ __launch_bounds__(256)
void gemm4(const float* __restrict__ h, const float* __restrict__ W,
           float* __restrict__ hw, int N, int K) {
    int g = blockIdx.x * 256 + threadIdx.x;
    int i = g >> 2, jq = g & 3;
    if (i >= N) return;
    if (jq * 4 >= F) return;
    const float4* hv = (const float4*)(h + (long)i * K);
    const float4* Wv = (const float4*)W;
    float4 acc = make_float4(0.f, 0.f, 0.f, 0.f);
    for (int k4 = 0; k4 < K / 4; ++k4) {
        float4 h4 = hv[k4];
        float4 w0 = Wv[(4 * k4 + 0) * (F / 4) + jq];
        acc.x = fmaf(h4.x, w0.x, acc.x); acc.y = fmaf(h4.x, w0.y, acc.y);
        acc.z = fmaf(h4.x, w0.z, acc.z); acc.w = fmaf(h4.x, w0.w, acc.w);
        float4 w1 = Wv[(4 * k4 + 1) * (F / 4) + jq];
        acc.x = fmaf(h4.y, w1.x, acc.x); acc.y = fmaf(h4.y, w1.y, acc.y);
        acc.z = fmaf(h4.y, w1.z, acc.z); acc.w = fmaf(h4.y, w1.w, acc.w);
        float4 w2 = Wv[(4 * k4 + 2) * (F / 4) + jq];
        acc.x = fmaf(h4.z, w2.x, acc.x); acc.y = fmaf(h4.z, w2.y, acc.y);
        acc.z = fmaf(h4.z, w2.z, acc.z); acc.w = fmaf(h4.z, w2.w, acc.w);
        float4 w3 = Wv[(4 * k4 + 3) * (F / 4) + jq];
        acc.x = fmaf(h4.w, w3.x, acc.x); acc.y = fmaf(h4.w, w3.y, acc.y);
        acc.z = fmaf(h4.w, w3.z, acc.z); acc.w = fmaf(h4.w, w3.w, acc.w);
    }
    ((float4*)hw)[(long)i * (F / 4) + jq] = acc;
}

template <int F>
__global__ __launch_bounds__(256)
void agg4(const float* __restrict__ hw, const int2* __restrict__ epack,
          const int* __restrict__ start, const float* __restrict__ selfw,
          const float* __restrict__ bias, float* __restrict__ out, int N) {
    int g = blockIdx.x * 256 + threadIdx.x;
    int node = g >> 2, fq = g & 3;
    if (node >= N) return;
    if (fq * 4 >= F) return;
    const float4* hwv = (const float4*)hw;
    int s = start[node], e = start[node + 1];
    float4 acc = make_float4(0.f, 0.f, 0.f, 0.f);
    for (int p = s; p < e; ++p) {
        int2 d = epack[p];
        float nm = __int_as_float(d.y);
        float4 gv = hwv[(long)d.x * (F / 4) + fq];
        acc.x = __fadd_rn(acc.x, __fmul_rn(nm, gv.x));
        acc.y = __fadd_rn(acc.y, __fmul_rn(nm, gv.y));
        acc.z = __fadd_rn(acc.z, __fmul_rn(nm, gv.z));
        acc.w = __fadd_rn(acc.w, __fmul_rn(nm, gv.w));
    }
    float sw = selfw[node];
    float4 sv = hwv[(long)node * (F / 4) + fq];
    acc.x = __fadd_rn(acc.x, __fmul_rn(sw, sv.x));
    acc.y = __fadd_rn(acc.y, __fmul_rn(sw, sv.y));
    acc.z = __fadd_rn(acc.z, __fmul_rn(sw, sv.z));
    acc.w = __fadd_rn(acc.w, __fmul_rn(sw, sv.w));
    float4 bv = ((const float4*)bias)[fq];
    acc.x = fmaxf(__fadd_rn(acc.x, bv.x), 0.f);
    acc.y = fmaxf(__fadd_rn(acc.y, bv.y), 0.f);
    acc.z = fmaxf(__fadd_rn(acc.z, bv.z), 0.f);
    acc.w = fmaxf(__fadd_rn(acc.w, bv.w), 0.f);
    ((float4*)out)[(long)node * (F / 4) + fq] = acc;
}

// ---------------------------------------------------------------------------

extern "C" void kernel_launch(void* const* d_in, const int* in_sizes, int n_in,
                              void* d_out, int out_size, void* d_ws, size_t ws_size,
                              hipStream_t stream) {
    const float* x      = (const float*)d_in[0];
    const int*   ei     = (const int*)d_in[1];
    const float* ew     = (const float*)d_in[2];
    const float* W0     = (const float*)d_in[3];
    const float* b0     = (const float*)d_in[4];
    const float* Wmid   = (const float*)d_in[5];
    const float* bmid   = (const float*)d_in[6];
    const float* Wlast  = (const float*)d_in[7];
    const float* blast  = (const float*)d_in[8];

    const int N = in_sizes[0] / DIN;              // 100000
    const int E = in_sizes[2];                    // 3200000
    const int* row32 = ei;
    const int* col32 = ei + E;
    const int nblk = (E + EPB - 1) / EPB;         // 782
    const int NB   = (N + CPB - 1) / CPB;         // 782 (<= NBMAX)

    char* w = (char*)d_ws;
    size_t off = 0;
    auto alloc = [&](size_t bytes) -> void* {
        void* p = w + off;
        off = (off + bytes + 255) & ~(size_t)255;
        return p;
    };
    int*  T      = (int*)alloc((size_t)NB * 4);
    int*  bStart = (int*)alloc((size_t)(NB + 1) * 4);
    int*  H      = (int*)alloc((size_t)nblk * NB * 4);
    int*  O      = (int*)alloc((size_t)nblk * NB * 4);
    int*  start  = (int*)alloc((size_t)(N + 1) * 4);
    float* dis   = (float*)alloc((size_t)N * 4);
    float* selfw = (float*)alloc((size_t)N * 4);
    int2* bins   = (int2*)alloc((size_t)E * 8);   // s3 out; becomes epack in s4
    float* hbuf  = (float*)alloc((size_t)N * HID * 4);
    float* hwbuf = (float*)alloc((size_t)N * HID * 4);
    (void)ws_size;

    hipMemsetAsync(T, 0, (size_t)NB * 4, stream);

    s1_hist<<<nblk, 256, 0, stream>>>(col32, H, T, E, N, NB);
    s2b_scan<<<1, 1024, 0, stream>>>(T, bStart, NB);
    s2c_scan<<<(NB * 64 + 255) / 256, 256, 0, stream>>>(H, bStart, O, NB, nblk);
    s3_bin<<<nblk, 256, 0, stream>>>(row32, col32, ew, O, bins, E, N, NB);
    s4_sort<<<NB, 256, 0, stream>>>(bStart, bins, start, dis, selfw, E, N);
    s7_norm<<<(N + 255) / 256, 256, 0, stream>>>(start, bins, dis, N);
    int2* epack = bins;

    int gridN4 = (N * 4 + 255) / 256;

    gemm4<HID><<<gridN4, 256, 0, stream>>>(x, W0, hwbuf, N, DIN);
    agg4<HID><<<gridN4, 256, 0, stream>>>(hwbuf, epack, start, selfw, b0, hbuf, N);

    for (int l = 0; l < NMID; l++) {
        gemm4<HID><<<gridN4, 256, 0, stream>>>(hbuf, Wmid + (size_t)l * HID * HID, hwbuf, N, HID);
        agg4<HID><<<gridN4, 256, 0, stream>>>(hwbuf, epack, start, selfw,
                                              bmid + (size_t)l * HID, hbuf, N);
    }

    gemm4<DOUT><<<gridN4, 256, 0, stream>>>(hbuf, Wlast, hwbuf, N, HID);
    agg4<DOUT><<<gridN4, 256, 0, stream>>>(hwbuf, epack, start, selfw, blast,
                                           (float*)d_out, N);
}